// Round 1
// 423.692 us; speedup vs baseline: 1.0660x; 1.0660x over previous
//
#include <hip/hip_runtime.h>
#include <math.h>

#define HID    2048
#define NH     16
#define HD     128
#define SEQ    2048
#define NBATCH 2
#define NT     (SEQ / 64)

typedef __attribute__((ext_vector_type(8))) short bf16x8;   // 8 bf16 = 4 VGPRs
typedef __attribute__((ext_vector_type(4))) float f32x4;    // MFMA accumulator

__device__ __forceinline__ short f2bf(float f) {            // fp32 -> bf16 RNE
    union { float f; unsigned u; } x; x.f = f;
    unsigned r = x.u + 0x7fffu + ((x.u >> 16) & 1u);
    return (short)(r >> 16);
}
__device__ __forceinline__ float bf2f(short s) {
    union { unsigned u; float f; } y;
    y.u = ((unsigned)(unsigned short)s) << 16;
    return y.f;
}

// async global->LDS, 16 B per lane; LDS dest = wave-uniform base + lane*16
__device__ __forceinline__ void gl_lds16(const short* g, short* l) {
    __builtin_amdgcn_global_load_lds(
        (const __attribute__((address_space(1))) unsigned int*)g,
        (__attribute__((address_space(3))) unsigned int*)l, 16, 0, 0);
}

// ---------------------------------------------------------------------------
// RoPE tables
// ---------------------------------------------------------------------------
__global__ __launch_bounds__(256) void rope_table_kernel(float* __restrict__ ct,
                                                         float* __restrict__ st) {
    int idx = blockIdx.x * 256 + threadIdx.x;
    if (idx >= SEQ * 64) return;
    int s = idx >> 6;
    int i = idx & 63;
    double inv = pow(10000.0, -(double)i / 64.0);
    float freq = (float)s * (float)inv;
    ct[idx] = cosf(freq);
    st[idx] = sinf(freq);
}

// ---------------------------------------------------------------------------
// fp32 -> bf16 (RNE) cast
// ---------------------------------------------------------------------------
__global__ __launch_bounds__(256) void split_h_kernel(const float* __restrict__ in,
                                                      short* __restrict__ oh, int n4) {
    int i = blockIdx.x * 256 + threadIdx.x;
    if (i >= n4) return;
    float4 v = ((const float4*)in)[i];
    short4 h;
    h.x = f2bf(v.x); h.y = f2bf(v.y); h.z = f2bf(v.z); h.w = f2bf(v.w);
    *(short4*)(oh + 4 * (size_t)i) = h;
}

// ---------------------------------------------------------------------------
// bf16 MFMA GEMM (m97 structure): C = A.B^T + bias, single bf16 chain.
// 128x128 tile, BK=32, 4 waves (2x2 of 64x64), 4x4 16x16x32 MFMAs.
// MODE 0: QKV -> RoPE (shfl pair) -> q (pre-scaled by 1/sqrt(d)) / k bf16
//         [b][h][s][d] + vT [b][h][d][s]
// MODE 1: out-proj -> fp32 C
// ---------------------------------------------------------------------------
#define LDSA 0
#define LDSB 4096

template <int MODE>
__global__ __launch_bounds__(256, 3) void gemm_bf16_kernel(
    const short* __restrict__ Ah, const short* __restrict__ Bh,
    const float* __restrict__ bias, float* __restrict__ C,
    short* __restrict__ qb, short* __restrict__ kbf, short* __restrict__ vTt,
    const float* __restrict__ ct, const float* __restrict__ st) {
    __shared__ short lds[MODE == 0 ? 18432 : 8192];  // staging 16 KB; V-transp 36 KB

    const int t     = threadIdx.x;
    const int w     = t >> 6;
    const int lane  = t & 63;
    const int mfrag = lane & 15;
    const int quad  = lane >> 4;
    const int wm    = (w >> 1) * 64;
    const int wn    = (w & 1) * 64;
    const int m0    = blockIdx.y * 128;
    const int n0    = blockIdx.x * 128;

    const int srow   = lane >> 2;
    const int schunk = (((lane & 3) ^ ((lane >> 3) & 3))) * 8;
    const short* gA0 = Ah + (size_t)(m0 + w * 16 + srow) * HID + schunk;
    const short* gA1 = Ah + (size_t)(m0 + 64 + w * 16 + srow) * HID + schunk;
    const short* gB0 = Bh + (size_t)(n0 + w * 16 + srow) * HID + schunk;
    const short* gB1 = Bh + (size_t)(n0 + 64 + w * 16 + srow) * HID + schunk;
    short* lA0 = &lds[LDSA + (w * 16) * 32];
    short* lA1 = &lds[LDSA + (64 + w * 16) * 32];
    short* lB0 = &lds[LDSB + (w * 16) * 32];
    short* lB1 = &lds[LDSB + (64 + w * 16) * 32];

    const int chA = 8 * (quad ^ ((mfrag >> 1) & 3));  // inverse swizzle

    f32x4 acc[4][4];
#pragma unroll
    for (int i = 0; i < 4; ++i)
#pragma unroll
        for (int j = 0; j < 4; ++j) acc[i][j] = (f32x4){0.f, 0.f, 0.f, 0.f};

    for (int kt = 0; kt < HID; kt += 32) {
        __syncthreads();
        gl_lds16(gA0 + kt, lA0);
        gl_lds16(gA1 + kt, lA1);
        gl_lds16(gB0 + kt, lB0);
        gl_lds16(gB1 + kt, lB1);
        __syncthreads();

        bf16x8 ah[4], bh[4];
#pragma unroll
        for (int mt = 0; mt < 4; ++mt)
            ah[mt] = *(const bf16x8*)&lds[LDSA + (wm + mt * 16 + mfrag) * 32 + chA];
#pragma unroll
        for (int nt = 0; nt < 4; ++nt)
            bh[nt] = *(const bf16x8*)&lds[LDSB + (wn + nt * 16 + mfrag) * 32 + chA];

#pragma unroll
        for (int mt = 0; mt < 4; ++mt)
#pragma unroll
            for (int nt = 0; nt < 4; ++nt)
                acc[mt][nt] = __builtin_amdgcn_mfma_f32_16x16x32_bf16(
                    ah[mt], bh[nt], acc[mt][nt], 0, 0, 0);
    }

    float bcol[4];
#pragma unroll
    for (int nt = 0; nt < 4; ++nt) bcol[nt] = bias[n0 + wn + nt * 16 + mfrag];

    if (MODE == 0) {
        const int which = n0 >> 11;          // 0=q 1=k 2=v
        const int h     = (n0 & 2047) >> 7;
        const int bidx  = m0 >> 11;
        if (which < 2) {
            short* dst = (which == 0) ? qb : kbf;
            const float post = (which == 0) ? 0.08838834764831845f : 1.0f;
#pragma unroll
            for (int mt = 0; mt < 4; ++mt)
#pragma unroll
                for (int r = 0; r < 4; ++r) {
                    int sl = (m0 & 2047) + wm + mt * 16 + 4 * quad + r;
#pragma unroll
                    for (int nt = 0; nt < 4; ++nt) {
                        float x  = acc[mt][nt][r] + bcol[nt];
                        float px = __shfl_xor(x, 1, 64);   // RoPE pair partner
                        int   d  = wn + nt * 16 + mfrag;
                        float c  = ct[sl * 64 + (d >> 1)];
                        float sn = st[sl * 64 + (d >> 1)];
                        float rot = (mfrag & 1) ? fmaf(px, sn, x * c)
                                                : (x * c - px * sn);
                        dst[((size_t)(bidx * NH + h) * SEQ + sl) * HD + d] =
                            f2bf(rot * post);
                    }
                }
        } else {
            // V: per-wave LDS transpose -> vT [b][h][d][s]
            __syncthreads();   // staging reads done; reuse LDS (which is per-block)
            short* tw = &lds[w * 4608];      // 64 x 72 shorts, wave-private
#pragma unroll
            for (int mt = 0; mt < 4; ++mt)
#pragma unroll
                for (int nt = 0; nt < 4; ++nt)
#pragma unroll
                    for (int r = 0; r < 4; ++r)
                        tw[(nt * 16 + mfrag) * 72 + (mt * 16 + 4 * quad + r)] =
                            f2bf(acc[mt][nt][r] + bcol[nt]);
            const size_t vbase = (size_t)(bidx * NH + h) * HD * SEQ;
            const int sbase = (m0 & 2047) + wm;
#pragma unroll
            for (int it = 0; it < 8; ++it) {
                int dl  = it * 8 + (lane >> 3);
                int cch = (lane & 7) ^ (lane >> 3);
                bf16x8 row = *(const bf16x8*)&tw[dl * 72 + cch * 8];
                *(bf16x8*)(vTt + vbase + (size_t)(wn + dl) * SEQ + sbase + cch * 8) = row;
            }
        }
    } else {
#pragma unroll
        for (int mt = 0; mt < 4; ++mt)
#pragma unroll
            for (int r = 0; r < 4; ++r) {
                int m = m0 + wm + mt * 16 + 4 * quad + r;
#pragma unroll
                for (int nt = 0; nt < 4; ++nt)
                    C[(size_t)m * HID + n0 + wn + nt * 16 + mfrag] =
                        acc[mt][nt][r] + bcol[nt];
            }
    }
}

// ---------------------------------------------------------------------------
// MFMA flash attention, 512-thread blocks (8 waves), q-tile 128 (16 rows/wave),
// KV tile 64, DOUBLE-BUFFERED (T3 minimum 2-phase): stage tile t+1 before
// computing tile t; ONE __syncthreads per tile (its vmcnt(0) drain is the
// prefetch wait -> load latency hides under a full compute phase).
// Softmax: per-lane partial row-sum (reduced once at epilogue), defer-max
// rescale (THR=8, T13), cvt_pk bf16 P-convert (T12 primitive), setprio (T5).
// LDS: K dbuf 32K | V dbuf 32K | P 16K (stride-64, XOR-swizzled) = 80 KB
//   -> 2 blocks/CU (grid = exactly 2/CU).
// ---------------------------------------------------------------------------
#define AK0 0
#define AK1 8192
#define AV0 16384
#define AV1 24576
#define AP  32768

__global__ __launch_bounds__(512, 4) void attn_mfma_kernel(
    const short* __restrict__ qb, const short* __restrict__ kbf,
    const short* __restrict__ vTt, const float* __restrict__ mask,
    short* __restrict__ ctxb) {
    __shared__ __align__(16) short lds[40960];   // 80 KB

    const int t    = threadIdx.x;
    const int w    = t >> 6;            // 0..7
    const int lane = t & 63;
    const int m    = lane & 15;
    const int quad = lane >> 4;

    // XCD swizzle: id&7 = XCD; 4 heads per XCD; 16 q-blocks per head
    const int id  = blockIdx.x;
    const int j   = id >> 3;
    const int bh  = (id & 7) * 4 + (j >> 4);
    const int q0  = (j & 15) * 128;
    const int b   = bh >> 4;
    const int h   = bh & 15;

    const size_t base = (size_t)bh * SEQ * HD;
    const short* kp = kbf + base;        // [s][d]
    const short* vp = vTt + base;        // [d][s]
    const float* mrow = mask + (size_t)b * SEQ;

    // staging addresses (swizzled source granule; LDS dest lane-contiguous)
    // K: 64 rows x 16 granules; wave w covers rows [w*8, w*8+8)
    // V: 128 rows x 8 granules;  wave w covers rows [w*16, w*16+16)
    size_t kOff[2], vOff[2];
    int kDst[2], vDst[2];
#pragma unroll
    for (int u = 0; u < 2; ++u) {
        int rk = w * 8 + u * 4 + (lane >> 4);
        int ck = (lane & 15) ^ (rk & 7);
        kOff[u] = (size_t)rk * HD + ck * 8;
        kDst[u] = (w * 8 + u * 4) * 128;
        int rv = w * 16 + u * 8 + (lane >> 3);
        int cv = (lane & 7) ^ (rv & 7);
        vOff[u] = (size_t)rv * SEQ + cv * 8;
        vDst[u] = (w * 16 + u * 8) * 64;
    }

    // Q fragments (16 rows/wave), direct global, once
    const int srow = q0 + w * 16 + m;
    bf16x8 qh[4];
    {
        const short* qhp = qb + base + (size_t)srow * HD;
#pragma unroll
        for (int c = 0; c < 4; ++c)
            qh[c] = *(const bf16x8*)(qhp + 32 * c + 8 * quad);
    }

    f32x4 O[8];
    float m_i[4], l_p[4];
#pragma unroll
    for (int c = 0; c < 8; ++c) O[c] = (f32x4){0.f, 0.f, 0.f, 0.f};
#pragma unroll
    for (int r = 0; r < 4; ++r) { m_i[r] = -INFINITY; l_p[r] = 0.f; }

    const int sw = m & 7;     // fragment-read inverse swizzle key
    const int pb = AP + w * 1024;      // wave-private P: 16 q-rows x 64 shorts
    const int kcb = (m >> 3);          // P k-chunk base bit
    const int ml  = m & 7;

    // prologue: stage tile 0 into buffer 0
#pragma unroll
    for (int u = 0; u < 2; ++u) {
        gl_lds16(kp + kOff[u], &lds[AK0 + kDst[u]]);
        gl_lds16(vp + vOff[u], &lds[AV0 + vDst[u]]);
    }

    for (int kt = 0; kt < NT; ++kt) {
        const int cur = kt & 1;
        const int k0  = kt * 64;

        // barrier: drains the prefetch issued last iteration (vmcnt(0)) and
        // makes sure all waves are done reading the buffer we stage into next
        __syncthreads();

        if (kt + 1 < NT) {
            const int nk0 = (kt + 1) * 64;
            const int nb  = cur ^ 1;
#pragma unroll
            for (int u = 0; u < 2; ++u) {
                gl_lds16(kp + (size_t)nk0 * HD + kOff[u],
                         &lds[(nb ? AK1 : AK0) + kDst[u]]);
                gl_lds16(vp + nk0 + vOff[u],
                         &lds[(nb ? AV1 : AV0) + vDst[u]]);
            }
        }

        const short* kb = &lds[cur ? AK1 : AK0];
        const short* vb = &lds[cur ? AV1 : AV0];

        float mk[4];
#pragma unroll
        for (int c2 = 0; c2 < 4; ++c2) mk[c2] = mrow[k0 + 16 * c2 + m];

        // ---- QK^T from LDS (Q pre-scaled) ----
        f32x4 S[4];
        __builtin_amdgcn_s_setprio(1);
#pragma unroll
        for (int c2 = 0; c2 < 4; ++c2) {
            f32x4 acc = (f32x4){0.f, 0.f, 0.f, 0.f};
#pragma unroll
            for (int c = 0; c < 4; ++c) {
                int pk = (4 * c + quad) ^ sw;
                bf16x8 kf = *(const bf16x8*)&kb[(16 * c2 + m) * 128 + pk * 8];
                acc = __builtin_amdgcn_mfma_f32_16x16x32_bf16(qh[c], kf, acc, 0, 0, 0);
            }
            S[c2] = acc;
        }
        __builtin_amdgcn_s_setprio(0);

        // ---- online softmax (defer-max, per-lane partial l) ----
        float rm4[4];
#pragma unroll
        for (int r = 0; r < 4; ++r) {
            float s0 = S[0][r] + mk[0];
            float s1 = S[1][r] + mk[1];
            float s2 = S[2][r] + mk[2];
            float s3 = S[3][r] + mk[3];
            S[0][r] = s0; S[1][r] = s1; S[2][r] = s2; S[3][r] = s3;
            float rm = fmaxf(fmaxf(s0, s1), fmaxf(s2, s3));
#pragma unroll
            for (int off = 1; off < 16; off <<= 1)
                rm = fmaxf(rm, __shfl_xor(rm, off, 64));
            rm4[r] = rm;
        }
        int needI = (rm4[0] > m_i[0] + 8.f) | (rm4[1] > m_i[1] + 8.f) |
                    (rm4[2] > m_i[2] + 8.f) | (rm4[3] > m_i[3] + 8.f);
        if (__any(needI)) {              // wave-uniform branch
#pragma unroll
            for (int r = 0; r < 4; ++r) {
                float mn = fmaxf(m_i[r], rm4[r]);
                float a  = __expf(m_i[r] - mn);
                m_i[r]   = mn;
                l_p[r]  *= a;
#pragma unroll
                for (int c = 0; c < 8; ++c) O[c][r] *= a;
            }
        }
        float p[4][4];
#pragma unroll
        for (int r = 0; r < 4; ++r) {
#pragma unroll
            for (int c2 = 0; c2 < 4; ++c2) p[c2][r] = __expf(S[c2][r] - m_i[r]);
            l_p[r] += (p[0][r] + p[1][r]) + (p[2][r] + p[3][r]);
        }

        // ---- P: C-layout -> A-layout via wave-private LDS (stride 64,
        //      chunk XOR-swizzled by q&7; packed bf16 convert) ----
#pragma unroll
        for (int c2 = 0; c2 < 4; ++c2) {
#pragma unroll
            for (int jj = 0; jj < 2; ++jj) {
                unsigned pkw;
                asm("v_cvt_pk_bf16_f32 %0, %1, %2"
                    : "=v"(pkw) : "v"(p[c2][2 * jj]), "v"(p[c2][2 * jj + 1]));
                int ql = 4 * quad + 2 * jj;
                int qh2 = ql + 1;
                lds[pb + ql * 64 + (((2 * c2 + kcb) ^ (ql & 7)) << 3) + ml] =
                    (short)(pkw & 0xffffu);
                lds[pb + qh2 * 64 + (((2 * c2 + kcb) ^ (qh2 & 7)) << 3) + ml] =
                    (short)(pkw >> 16);
            }
        }

        // ---- PV from LDS ----
        __builtin_amdgcn_s_setprio(1);
#pragma unroll
        for (int cc = 0; cc < 2; ++cc) {
            int pv = (4 * cc + quad) ^ sw;
            bf16x8 pf = *(const bf16x8*)&lds[pb + m * 64 + (pv << 3)];
#pragma unroll
            for (int c = 0; c < 8; ++c) {
                bf16x8 vf = *(const bf16x8*)&vb[(16 * c + m) * 64 + pv * 8];
                O[c] = __builtin_amdgcn_mfma_f32_16x16x32_bf16(pf, vf, O[c], 0, 0, 0);
            }
        }
        __builtin_amdgcn_s_setprio(0);
    }

    // ---- epilogue: reduce partial l across the 16-lane row group, store ----
#pragma unroll
    for (int r = 0; r < 4; ++r) {
        float lv = l_p[r];
#pragma unroll
        for (int off = 1; off < 16; off <<= 1) lv += __shfl_xor(lv, off, 64);
        float inv = 1.0f / lv;
        int s = q0 + w * 16 + 4 * quad + r;
        size_t off2 = ((size_t)(b * SEQ + s)) * HID + h * HD;
#pragma unroll
        for (int c = 0; c < 8; ++c)
            ctxb[off2 + 16 * c + m] = f2bf(O[c][r] * inv);
    }
}

// ---------------------------------------------------------------------------
extern "C" void kernel_launch(void* const* d_in, const int* in_sizes, int n_in,
                              void* d_out, int out_size, void* d_ws, size_t ws_size,
                              hipStream_t stream) {
    const float* hs   = (const float*)d_in[0];
    const float* mask = (const float*)d_in[1];
    const float* Wqkv = (const float*)d_in[2];
    const float* bqkv = (const float*)d_in[3];
    const float* Wout = (const float*)d_in[4];
    const float* bout = (const float*)d_in[5];
    float* out = (float*)d_out;

    const size_t qkv_elems = (size_t)NBATCH * NH * SEQ * HD;  // 8.39M
    char* p = (char*)d_ws;
    float* cos_t = (float*)p; p += (size_t)SEQ * 64 * 4;
    float* sin_t = (float*)p; p += (size_t)SEQ * 64 * 4;
    short* qbf   = (short*)p; p += qkv_elems * 2;
    short* kbf   = (short*)p; p += qkv_elems * 2;
    short* vTt   = (short*)p; p += qkv_elems * 2;
    short* Wqkvh = (short*)p; p += (size_t)3 * HID * HID * 2;
    short* Wouth = (short*)p; p += (size_t)HID * HID * 2;
    short* Ahs   = (short*)p; p += qkv_elems * 2;   // bf16(hs); aliased ctx after QKV
    short* ctxb  = Ahs;

    rope_table_kernel<<<(SEQ * 64 + 255) / 256, 256, 0, stream>>>(cos_t, sin_t);

    split_h_kernel<<<(int)(qkv_elems / 4 / 256), 256, 0, stream>>>(
        hs, Ahs, (int)(qkv_elems / 4));
    split_h_kernel<<<(int)((size_t)3 * HID * HID / 4 / 256), 256, 0, stream>>>(
        Wqkv, Wqkvh, (int)((size_t)3 * HID * HID / 4));
    split_h_kernel<<<(int)((size_t)HID * HID / 4 / 256), 256, 0, stream>>>(
        Wout, Wouth, (int)((size_t)HID * HID / 4));

    // QKV: M=4096, N=6144, K=2048 (bf16 MFMA, single chain)
    gemm_bf16_kernel<0><<<dim3(48, 32), 256, 0, stream>>>(
        Ahs, Wqkvh, bqkv, nullptr, qbf, kbf, vTt, cos_t, sin_t);

    // attention: 512 XCD-swizzled blocks of 512 threads
    attn_mfma_kernel<<<512, 512, 0, stream>>>(qbf, kbf, vTt, mask, ctxb);

    // out-proj: M=4096, N=2048, K=2048
    gemm_bf16_kernel<1><<<dim3(16, 32), 256, 0, stream>>>(
        ctxb, Wouth, bout, out, nullptr, nullptr, nullptr, nullptr, nullptr);
}

// Round 2
// 422.150 us; speedup vs baseline: 1.0699x; 1.0037x over previous
//
#include <hip/hip_runtime.h>
#include <math.h>

#define HID    2048
#define NH     16
#define HD     128
#define SEQ    2048
#define NBATCH 2
#define NT     (SEQ / 64)

typedef __attribute__((ext_vector_type(8))) short bf16x8;   // 8 bf16 = 4 VGPRs
typedef __attribute__((ext_vector_type(4))) float f32x4;    // MFMA accumulator

__device__ __forceinline__ short f2bf(float f) {            // fp32 -> bf16 RNE
    union { float f; unsigned u; } x; x.f = f;
    unsigned r = x.u + 0x7fffu + ((x.u >> 16) & 1u);
    return (short)(r >> 16);
}
__device__ __forceinline__ float bf2f(short s) {
    union { unsigned u; float f; } y;
    y.u = ((unsigned)(unsigned short)s) << 16;
    return y.f;
}

// async global->LDS, 16 B per lane; LDS dest = wave-uniform base + lane*16
__device__ __forceinline__ void gl_lds16(const short* g, short* l) {
    __builtin_amdgcn_global_load_lds(
        (const __attribute__((address_space(1))) unsigned int*)g,
        (__attribute__((address_space(3))) unsigned int*)l, 16, 0, 0);
}

// ---------------------------------------------------------------------------
// RoPE table: fused float2 (cos,sin), duplicated across each pair half:
// cst[s*HD + d] = (cos(s*inv(d>>1)), sin(s*inv(d>>1)))  -> one coalesced
// 8-B load per epilogue element instead of two half-utilized 4-B loads.
// ---------------------------------------------------------------------------
__global__ __launch_bounds__(256) void rope_table_kernel(float2* __restrict__ cst) {
    int idx = blockIdx.x * 256 + threadIdx.x;
    if (idx >= SEQ * 64) return;
    int s = idx >> 6;
    int i = idx & 63;
    double inv = pow(10000.0, -(double)i / 64.0);
    float freq = (float)s * (float)inv;
    float2 cs = make_float2(cosf(freq), sinf(freq));
    cst[s * HD + 2 * i]     = cs;
    cst[s * HD + 2 * i + 1] = cs;
}

// ---------------------------------------------------------------------------
// fp32 -> bf16 (RNE) cast
// ---------------------------------------------------------------------------
__global__ __launch_bounds__(256) void split_h_kernel(const float* __restrict__ in,
                                                      short* __restrict__ oh, int n4) {
    int i = blockIdx.x * 256 + threadIdx.x;
    if (i >= n4) return;
    float4 v = ((const float4*)in)[i];
    short4 h;
    h.x = f2bf(v.x); h.y = f2bf(v.y); h.z = f2bf(v.z); h.w = f2bf(v.w);
    *(short4*)(oh + 4 * (size_t)i) = h;
}

// ---------------------------------------------------------------------------
// bf16 MFMA GEMM (m97 structure): C = A.B^T + bias, single bf16 chain.
// 128x128 tile, BK=32, 4 waves (2x2 of 64x64), 4x4 16x16x32 MFMAs.
// MODE 0: QKV -> RoPE (shfl pair) -> q (pre-scaled by 1/sqrt(d)) / k bf16
//         [b][h][s][d] + vT [b][h][d][s]
// MODE 1: out-proj -> fp32 C
// ---------------------------------------------------------------------------
#define LDSA 0
#define LDSB 4096

template <int MODE>
__global__ __launch_bounds__(256, 3) void gemm_bf16_kernel(
    const short* __restrict__ Ah, const short* __restrict__ Bh,
    const float* __restrict__ bias, float* __restrict__ C,
    short* __restrict__ qb, short* __restrict__ kbf, short* __restrict__ vTt,
    const float2* __restrict__ cst) {
    __shared__ short lds[MODE == 0 ? 18432 : 8192];  // staging 16 KB; V-transp 36 KB

    const int t     = threadIdx.x;
    const int w     = t >> 6;
    const int lane  = t & 63;
    const int mfrag = lane & 15;
    const int quad  = lane >> 4;
    const int wm    = (w >> 1) * 64;
    const int wn    = (w & 1) * 64;
    const int m0    = blockIdx.y * 128;
    const int n0    = blockIdx.x * 128;

    const int srow   = lane >> 2;
    const int schunk = (((lane & 3) ^ ((lane >> 3) & 3))) * 8;
    const short* gA0 = Ah + (size_t)(m0 + w * 16 + srow) * HID + schunk;
    const short* gA1 = Ah + (size_t)(m0 + 64 + w * 16 + srow) * HID + schunk;
    const short* gB0 = Bh + (size_t)(n0 + w * 16 + srow) * HID + schunk;
    const short* gB1 = Bh + (size_t)(n0 + 64 + w * 16 + srow) * HID + schunk;
    short* lA0 = &lds[LDSA + (w * 16) * 32];
    short* lA1 = &lds[LDSA + (64 + w * 16) * 32];
    short* lB0 = &lds[LDSB + (w * 16) * 32];
    short* lB1 = &lds[LDSB + (64 + w * 16) * 32];

    const int chA = 8 * (quad ^ ((mfrag >> 1) & 3));  // inverse swizzle

    f32x4 acc[4][4];
#pragma unroll
    for (int i = 0; i < 4; ++i)
#pragma unroll
        for (int j = 0; j < 4; ++j) acc[i][j] = (f32x4){0.f, 0.f, 0.f, 0.f};

    for (int kt = 0; kt < HID; kt += 32) {
        __syncthreads();
        gl_lds16(gA0 + kt, lA0);
        gl_lds16(gA1 + kt, lA1);
        gl_lds16(gB0 + kt, lB0);
        gl_lds16(gB1 + kt, lB1);
        __syncthreads();

        bf16x8 ah[4], bh[4];
#pragma unroll
        for (int mt = 0; mt < 4; ++mt)
            ah[mt] = *(const bf16x8*)&lds[LDSA + (wm + mt * 16 + mfrag) * 32 + chA];
#pragma unroll
        for (int nt = 0; nt < 4; ++nt)
            bh[nt] = *(const bf16x8*)&lds[LDSB + (wn + nt * 16 + mfrag) * 32 + chA];

#pragma unroll
        for (int mt = 0; mt < 4; ++mt)
#pragma unroll
            for (int nt = 0; nt < 4; ++nt)
                acc[mt][nt] = __builtin_amdgcn_mfma_f32_16x16x32_bf16(
                    ah[mt], bh[nt], acc[mt][nt], 0, 0, 0);
    }

    float bcol[4];
#pragma unroll
    for (int nt = 0; nt < 4; ++nt) bcol[nt] = bias[n0 + wn + nt * 16 + mfrag];

    if (MODE == 0) {
        const int which = n0 >> 11;          // 0=q 1=k 2=v
        const int h     = (n0 & 2047) >> 7;
        const int bidx  = m0 >> 11;
        if (which < 2) {
            short* dst = (which == 0) ? qb : kbf;
            const float post = (which == 0) ? 0.08838834764831845f : 1.0f;
#pragma unroll
            for (int mt = 0; mt < 4; ++mt)
#pragma unroll
                for (int r = 0; r < 4; ++r) {
                    int sl = (m0 & 2047) + wm + mt * 16 + 4 * quad + r;
                    const float2* csr = cst + (size_t)sl * HD;
#pragma unroll
                    for (int nt = 0; nt < 4; ++nt) {
                        float x  = acc[mt][nt][r] + bcol[nt];
                        float px = __shfl_xor(x, 1, 64);   // RoPE pair partner
                        int   d  = wn + nt * 16 + mfrag;
                        float2 cs = csr[d];                 // one coalesced 8B load
                        float rot = (mfrag & 1) ? fmaf(px, cs.y, x * cs.x)
                                                : (x * cs.x - px * cs.y);
                        dst[((size_t)(bidx * NH + h) * SEQ + sl) * HD + d] =
                            f2bf(rot * post);
                    }
                }
        } else {
            // V: per-wave LDS transpose -> vT [b][h][d][s]
            __syncthreads();   // staging reads done; reuse LDS (which is per-block)
            short* tw = &lds[w * 4608];      // 64 x 72 shorts, wave-private
#pragma unroll
            for (int mt = 0; mt < 4; ++mt)
#pragma unroll
                for (int nt = 0; nt < 4; ++nt)
#pragma unroll
                    for (int r = 0; r < 4; ++r)
                        tw[(nt * 16 + mfrag) * 72 + (mt * 16 + 4 * quad + r)] =
                            f2bf(acc[mt][nt][r] + bcol[nt]);
            const size_t vbase = (size_t)(bidx * NH + h) * HD * SEQ;
            const int sbase = (m0 & 2047) + wm;
#pragma unroll
            for (int it = 0; it < 8; ++it) {
                int dl  = it * 8 + (lane >> 3);
                int cch = (lane & 7) ^ (lane >> 3);
                bf16x8 row = *(const bf16x8*)&tw[dl * 72 + cch * 8];
                *(bf16x8*)(vTt + vbase + (size_t)(wn + dl) * SEQ + sbase + cch * 8) = row;
            }
        }
    } else {
#pragma unroll
        for (int mt = 0; mt < 4; ++mt)
#pragma unroll
            for (int r = 0; r < 4; ++r) {
                int m = m0 + wm + mt * 16 + 4 * quad + r;
#pragma unroll
                for (int nt = 0; nt < 4; ++nt)
                    C[(size_t)m * HID + n0 + wn + nt * 16 + mfrag] =
                        acc[mt][nt][r] + bcol[nt];
            }
    }
}

// ---------------------------------------------------------------------------
// MFMA flash attention, 512-thread blocks (8 waves), q-tile 128 (16 rows/wave),
// KV tile 64, DOUBLE-BUFFERED (T3 minimum 2-phase): stage tile t+1 before
// computing tile t; ONE __syncthreads per tile (its vmcnt(0) drain is the
// prefetch wait -> load latency hides under a full compute phase).
// Softmax: per-lane partial row-sum (reduced once at epilogue), defer-max
// rescale (THR=8, T13), cvt_pk bf16 P-convert (T12 primitive), setprio (T5).
// LDS: K dbuf 32K | V dbuf 32K | P 16K (stride-64, XOR-swizzled) = 80 KB
//   -> 2 blocks/CU (grid = exactly 2/CU).
// ---------------------------------------------------------------------------
#define AK0 0
#define AK1 8192
#define AV0 16384
#define AV1 24576
#define AP  32768

__global__ __launch_bounds__(512, 4) void attn_mfma_kernel(
    const short* __restrict__ qb, const short* __restrict__ kbf,
    const short* __restrict__ vTt, const float* __restrict__ mask,
    short* __restrict__ ctxb) {
    __shared__ __align__(16) short lds[40960];   // 80 KB

    const int t    = threadIdx.x;
    const int w    = t >> 6;            // 0..7
    const int lane = t & 63;
    const int m    = lane & 15;
    const int quad = lane >> 4;

    // XCD swizzle: id&7 = XCD; 4 heads per XCD; 16 q-blocks per head
    const int id  = blockIdx.x;
    const int j   = id >> 3;
    const int bh  = (id & 7) * 4 + (j >> 4);
    const int q0  = (j & 15) * 128;
    const int b   = bh >> 4;
    const int h   = bh & 15;

    const size_t base = (size_t)bh * SEQ * HD;
    const short* kp = kbf + base;        // [s][d]
    const short* vp = vTt + base;        // [d][s]
    const float* mrow = mask + (size_t)b * SEQ;

    // staging addresses (swizzled source granule; LDS dest lane-contiguous)
    // K: 64 rows x 16 granules; wave w covers rows [w*8, w*8+8)
    // V: 128 rows x 8 granules;  wave w covers rows [w*16, w*16+16)
    size_t kOff[2], vOff[2];
    int kDst[2], vDst[2];
#pragma unroll
    for (int u = 0; u < 2; ++u) {
        int rk = w * 8 + u * 4 + (lane >> 4);
        int ck = (lane & 15) ^ (rk & 7);
        kOff[u] = (size_t)rk * HD + ck * 8;
        kDst[u] = (w * 8 + u * 4) * 128;
        int rv = w * 16 + u * 8 + (lane >> 3);
        int cv = (lane & 7) ^ (rv & 7);
        vOff[u] = (size_t)rv * SEQ + cv * 8;
        vDst[u] = (w * 16 + u * 8) * 64;
    }

    // Q fragments (16 rows/wave), direct global, once
    const int srow = q0 + w * 16 + m;
    bf16x8 qh[4];
    {
        const short* qhp = qb + base + (size_t)srow * HD;
#pragma unroll
        for (int c = 0; c < 4; ++c)
            qh[c] = *(const bf16x8*)(qhp + 32 * c + 8 * quad);
    }

    f32x4 O[8];
    float m_i[4], l_p[4];
#pragma unroll
    for (int c = 0; c < 8; ++c) O[c] = (f32x4){0.f, 0.f, 0.f, 0.f};
#pragma unroll
    for (int r = 0; r < 4; ++r) { m_i[r] = -INFINITY; l_p[r] = 0.f; }

    const int sw = m & 7;     // fragment-read inverse swizzle key
    const int pb = AP + w * 1024;      // wave-private P: 16 q-rows x 64 shorts
    const int kcb = (m >> 3);          // P k-chunk base bit
    const int ml  = m & 7;

    // prologue: stage tile 0 into buffer 0
#pragma unroll
    for (int u = 0; u < 2; ++u) {
        gl_lds16(kp + kOff[u], &lds[AK0 + kDst[u]]);
        gl_lds16(vp + vOff[u], &lds[AV0 + vDst[u]]);
    }

    for (int kt = 0; kt < NT; ++kt) {
        const int cur = kt & 1;
        const int k0  = kt * 64;

        // barrier: drains the prefetch issued last iteration (vmcnt(0)) and
        // makes sure all waves are done reading the buffer we stage into next
        __syncthreads();

        if (kt + 1 < NT) {
            const int nk0 = (kt + 1) * 64;
            const int nb  = cur ^ 1;
#pragma unroll
            for (int u = 0; u < 2; ++u) {
                gl_lds16(kp + (size_t)nk0 * HD + kOff[u],
                         &lds[(nb ? AK1 : AK0) + kDst[u]]);
                gl_lds16(vp + nk0 + vOff[u],
                         &lds[(nb ? AV1 : AV0) + vDst[u]]);
            }
        }

        const short* kb = &lds[cur ? AK1 : AK0];
        const short* vb = &lds[cur ? AV1 : AV0];

        float mk[4];
#pragma unroll
        for (int c2 = 0; c2 < 4; ++c2) mk[c2] = mrow[k0 + 16 * c2 + m];

        // ---- QK^T from LDS (Q pre-scaled) ----
        f32x4 S[4];
        __builtin_amdgcn_s_setprio(1);
#pragma unroll
        for (int c2 = 0; c2 < 4; ++c2) {
            f32x4 acc = (f32x4){0.f, 0.f, 0.f, 0.f};
#pragma unroll
            for (int c = 0; c < 4; ++c) {
                int pk = (4 * c + quad) ^ sw;
                bf16x8 kf = *(const bf16x8*)&kb[(16 * c2 + m) * 128 + pk * 8];
                acc = __builtin_amdgcn_mfma_f32_16x16x32_bf16(qh[c], kf, acc, 0, 0, 0);
            }
            S[c2] = acc;
        }
        __builtin_amdgcn_s_setprio(0);

        // ---- online softmax (defer-max, per-lane partial l) ----
        float rm4[4];
#pragma unroll
        for (int r = 0; r < 4; ++r) {
            float s0 = S[0][r] + mk[0];
            float s1 = S[1][r] + mk[1];
            float s2 = S[2][r] + mk[2];
            float s3 = S[3][r] + mk[3];
            S[0][r] = s0; S[1][r] = s1; S[2][r] = s2; S[3][r] = s3;
            float rm = fmaxf(fmaxf(s0, s1), fmaxf(s2, s3));
#pragma unroll
            for (int off = 1; off < 16; off <<= 1)
                rm = fmaxf(rm, __shfl_xor(rm, off, 64));
            rm4[r] = rm;
        }
        int needI = (rm4[0] > m_i[0] + 8.f) | (rm4[1] > m_i[1] + 8.f) |
                    (rm4[2] > m_i[2] + 8.f) | (rm4[3] > m_i[3] + 8.f);
        if (__any(needI)) {              // wave-uniform branch
#pragma unroll
            for (int r = 0; r < 4; ++r) {
                float mn = fmaxf(m_i[r], rm4[r]);
                float a  = __expf(m_i[r] - mn);
                m_i[r]   = mn;
                l_p[r]  *= a;
#pragma unroll
                for (int c = 0; c < 8; ++c) O[c][r] *= a;
            }
        }
        float p[4][4];
#pragma unroll
        for (int r = 0; r < 4; ++r) {
#pragma unroll
            for (int c2 = 0; c2 < 4; ++c2) p[c2][r] = __expf(S[c2][r] - m_i[r]);
            l_p[r] += (p[0][r] + p[1][r]) + (p[2][r] + p[3][r]);
        }

        // ---- P: C-layout -> A-layout via wave-private LDS (stride 64,
        //      chunk XOR-swizzled by q&7; packed bf16 convert) ----
#pragma unroll
        for (int c2 = 0; c2 < 4; ++c2) {
#pragma unroll
            for (int jj = 0; jj < 2; ++jj) {
                unsigned pkw;
                asm("v_cvt_pk_bf16_f32 %0, %1, %2"
                    : "=v"(pkw) : "v"(p[c2][2 * jj]), "v"(p[c2][2 * jj + 1]));
                int ql = 4 * quad + 2 * jj;
                int qh2 = ql + 1;
                lds[pb + ql * 64 + (((2 * c2 + kcb) ^ (ql & 7)) << 3) + ml] =
                    (short)(pkw & 0xffffu);
                lds[pb + qh2 * 64 + (((2 * c2 + kcb) ^ (qh2 & 7)) << 3) + ml] =
                    (short)(pkw >> 16);
            }
        }

        // ---- PV from LDS ----
        __builtin_amdgcn_s_setprio(1);
#pragma unroll
        for (int cc = 0; cc < 2; ++cc) {
            int pv = (4 * cc + quad) ^ sw;
            bf16x8 pf = *(const bf16x8*)&lds[pb + m * 64 + (pv << 3)];
#pragma unroll
            for (int c = 0; c < 8; ++c) {
                bf16x8 vf = *(const bf16x8*)&vb[(16 * c + m) * 64 + pv * 8];
                O[c] = __builtin_amdgcn_mfma_f32_16x16x32_bf16(pf, vf, O[c], 0, 0, 0);
            }
        }
        __builtin_amdgcn_s_setprio(0);
    }

    // ---- epilogue: reduce partial l across the 16-lane row group, store ----
#pragma unroll
    for (int r = 0; r < 4; ++r) {
        float lv = l_p[r];
#pragma unroll
        for (int off = 1; off < 16; off <<= 1) lv += __shfl_xor(lv, off, 64);
        float inv = 1.0f / lv;
        int s = q0 + w * 16 + 4 * quad + r;
        size_t off2 = ((size_t)(b * SEQ + s)) * HID + h * HD;
#pragma unroll
        for (int c = 0; c < 8; ++c)
            ctxb[off2 + 16 * c + m] = f2bf(O[c][r] * inv);
    }
}

// ---------------------------------------------------------------------------
extern "C" void kernel_launch(void* const* d_in, const int* in_sizes, int n_in,
                              void* d_out, int out_size, void* d_ws, size_t ws_size,
                              hipStream_t stream) {
    const float* hs   = (const float*)d_in[0];
    const float* mask = (const float*)d_in[1];
    const float* Wqkv = (const float*)d_in[2];
    const float* bqkv = (const float*)d_in[3];
    const float* Wout = (const float*)d_in[4];
    const float* bout = (const float*)d_in[5];
    float* out = (float*)d_out;

    const size_t qkv_elems = (size_t)NBATCH * NH * SEQ * HD;  // 8.39M
    char* p = (char*)d_ws;
    float2* cst  = (float2*)p; p += (size_t)SEQ * HD * 8;   // fused cos/sin, 2 MB
    short* qbf   = (short*)p; p += qkv_elems * 2;
    short* kbf   = (short*)p; p += qkv_elems * 2;
    short* vTt   = (short*)p; p += qkv_elems * 2;
    short* Wqkvh = (short*)p; p += (size_t)3 * HID * HID * 2;
    short* Wouth = (short*)p; p += (size_t)HID * HID * 2;
    short* Ahs   = (short*)p; p += qkv_elems * 2;   // bf16(hs); aliased ctx after QKV
    short* ctxb  = Ahs;

    rope_table_kernel<<<(SEQ * 64 + 255) / 256, 256, 0, stream>>>(cst);

    split_h_kernel<<<(int)(qkv_elems / 4 / 256), 256, 0, stream>>>(
        hs, Ahs, (int)(qkv_elems / 4));
    split_h_kernel<<<(int)((size_t)3 * HID * HID / 4 / 256), 256, 0, stream>>>(
        Wqkv, Wqkvh, (int)((size_t)3 * HID * HID / 4));
    split_h_kernel<<<(int)((size_t)HID * HID / 4 / 256), 256, 0, stream>>>(
        Wout, Wouth, (int)((size_t)HID * HID / 4));

    // QKV: M=4096, N=6144, K=2048 (bf16 MFMA, single chain)
    gemm_bf16_kernel<0><<<dim3(48, 32), 256, 0, stream>>>(
        Ahs, Wqkvh, bqkv, nullptr, qbf, kbf, vTt, cst);

    // attention: 512 XCD-swizzled blocks of 512 threads
    attn_mfma_kernel<<<512, 512, 0, stream>>>(qbf, kbf, vTt, mask, ctxb);

    // out-proj: M=4096, N=2048, K=2048
    gemm_bf16_kernel<1><<<dim3(16, 32), 256, 0, stream>>>(
        ctxb, Wouth, bout, out, nullptr, nullptr, nullptr, nullptr);
}